// Round 1
// 3812.365 us; speedup vs baseline: 1.1316x; 1.1316x over previous
//
#include <hip/hip_runtime.h>

#define cB 16
#define cS 512
#define cD 512
#define cL 64
#define cG 8     // blocks per batch
#define cT 512   // threads per block

// ---------------- workspace layout (bytes) ----------------
constexpr size_t FCOPY   = (size_t)cB * cS * cD * 4;            // 16 MB per F copy
constexpr size_t OFF_F0  = 0;
constexpr size_t OFF_F1  = FCOPY;
constexpr size_t OFF_U   = 2 * FCOPY;                           // D f32
constexpr size_t OFF_V   = OFF_U  + 2048;
constexpr size_t OFF_UA  = OFF_V  + 2048;                       // W1a @ u
constexpr size_t OFF_UB  = OFF_UA + 2048;                       // W1b @ u
constexpr size_t OFF_VA  = OFF_UB + 2048;                       // W1a @ v
constexpr size_t OFF_VB  = OFF_VA + 2048;                       // W1b @ v
constexpr size_t OFF_SC  = OFF_VB + 2048;                       // [c0, cu, cv]
constexpr size_t OFF_SI  = OFF_SC + 64;                         // B*S f32
constexpr size_t OFF_SJ  = OFF_SI + (size_t)cB*cS*4;
constexpr size_t OFF_CLS = OFF_SJ + (size_t)cB*cS*4;
constexpr size_t OFF_ADJ = OFF_CLS+ (size_t)cB*cS*4;            // B*S*8 u64 (row-major)
constexpr size_t OFF_RM  = OFF_ADJ+ (size_t)cB*cS*64;
constexpr size_t OFF_RA  = OFF_RM + (size_t)cB*cS*4;
// prog: per batch 8 counters at 128B stride (no false sharing). 16 KB total.
constexpr size_t OFF_BAR = ((OFF_RA + (size_t)cB*cS*4 + 127) & ~(size_t)127);

// ---------------- DPP max+key reduction helpers (order-independent) ----------
// max with (>, ==&&key<) total order => any reduction tree gives identical
// result bit-for-bit, so DPP replaces ds_bpermute-based __shfl chains for free.
template <int CTRL, int RMASK>
__device__ __forceinline__ void dpp_max_step(float& v, int& k) {
    const float ov = __int_as_float(__builtin_amdgcn_update_dpp(
        (int)0xff800000u, __float_as_int(v), CTRL, RMASK, 0xf, false));
    const int ok = __builtin_amdgcn_update_dpp(
        0x7fffffff, k, CTRL, RMASK, 0xf, false);
    if (ov > v || (ov == v && ok < k)) { v = ov; k = ok; }
}

// full 64-lane (value,key) max; result lands in lane 63
__device__ __forceinline__ void wave_max64(float& v, int& k) {
    dpp_max_step<0x111, 0xf>(v, k);   // row_shr:1
    dpp_max_step<0x112, 0xf>(v, k);   // row_shr:2
    dpp_max_step<0x114, 0xf>(v, k);   // row_shr:4
    dpp_max_step<0x118, 0xf>(v, k);   // row_shr:8
    dpp_max_step<0x142, 0xa>(v, k);   // row_bcast:15 rows 1,3
    dpp_max_step<0x143, 0xc>(v, k);   // row_bcast:31 rows 2,3
}

// ---------------- K1: u = W1a@w2, v = W1b@w2, c0 = b1@w2 + b2 ----------------
__global__ void k1_uvc(const float* __restrict__ W1, const float* __restrict__ b1,
                       const float* __restrict__ w2, const float* __restrict__ b2,
                       char* __restrict__ ws) {
    const int t = threadIdx.x;
    const int r = blockIdx.x;
    if (r == 1025) {   // zero progress counters (ws poisoned 0xAA pre-launch)
        unsigned* bar = (unsigned*)(ws + OFF_BAR);
        for (int i = t; i < 4096; i += 256) bar[i] = 0u;
        return;
    }
    __shared__ float rs[256];
    float acc;
    if (r < 1024) {
        const float* row = W1 + (size_t)r * cD;
        acc = row[t] * w2[t] + row[t + 256] * w2[t + 256];
    } else {
        acc = b1[t] * w2[t] + b1[t + 256] * w2[t + 256];
    }
    rs[t] = acc; __syncthreads();
    for (int o = 128; o; o >>= 1) { if (t < o) rs[t] += rs[t + o]; __syncthreads(); }
    if (t == 0) {
        if (r < 512)        ((float*)(ws + OFF_U))[r] = rs[0];
        else if (r < 1024)  ((float*)(ws + OFF_V))[r - 512] = rs[0];
        else                ((float*)(ws + OFF_SC))[0] = rs[0] + b2[0];   // c0
    }
}

// ---------------- K1b: ua/ub/va/vb = W1{a,b} @ {u,v};  cu = b1·u, cv = b1·v --------
__global__ void k1b_proj(const float* __restrict__ W1, const float* __restrict__ b1,
                         char* __restrict__ ws) {
    __shared__ float ru[256], rv[256];
    const int t = threadIdx.x;
    const int k = blockIdx.x;
    const float* U = (const float*)(ws + OFF_U);
    const float* V = (const float*)(ws + OFF_V);
    const float* row = (k < 1024) ? (W1 + (size_t)k * cD) : b1;
    ru[t] = row[t] * U[t] + row[t + 256] * U[t + 256];
    rv[t] = row[t] * V[t] + row[t + 256] * V[t + 256];
    __syncthreads();
    for (int o = 128; o; o >>= 1) {
        if (t < o) { ru[t] += ru[t + o]; rv[t] += rv[t + o]; }
        __syncthreads();
    }
    if (t == 0) {
        if (k < 512)       { ((float*)(ws + OFF_UA))[k] = ru[0]; ((float*)(ws + OFF_VA))[k] = rv[0]; }
        else if (k < 1024) { ((float*)(ws + OFF_UB))[k - 512] = ru[0]; ((float*)(ws + OFF_VB))[k - 512] = rv[0]; }
        else               { ((float*)(ws + OFF_SC))[1] = ru[0]; ((float*)(ws + OFF_SC))[2] = rv[0]; }
    }
}

// ---------------- K2: gather feats into F copy0, si = f@u, sj = f@v ----------------
__global__ void k2_feat(const int* __restrict__ tok, const float* __restrict__ emb,
                        char* __restrict__ ws) {
    __shared__ float ru[256], rv[256];
    const int t = threadIdx.x;
    const int bs = blockIdx.x;
    const float* U = (const float*)(ws + OFF_U);
    const float* V = (const float*)(ws + OFF_V);
    float* F = (float*)(ws + OFF_F0);
    const int tk = tok[bs];
    const float* src = emb + (size_t)tk * cD;
    float* dst = F + (size_t)bs * cD;
    const float e0 = src[t], e1 = src[t + 256];
    dst[t] = e0; dst[t + 256] = e1;
    ru[t] = e0 * U[t] + e1 * U[t + 256];
    rv[t] = e0 * V[t] + e1 * V[t + 256];
    __syncthreads();
    for (int o = 128; o; o >>= 1) {
        if (t < o) { ru[t] += ru[t + o]; rv[t] += rv[t + o]; }
        __syncthreads();
    }
    if (t == 0) {
        ((float*)(ws + OFF_SI))[bs] = ru[0];
        ((float*)(ws + OFF_SJ))[bs] = rv[0];
    }
}

// ---------------- K3: logits argmax -> cls ----------------
__global__ void k3_cls(const float* __restrict__ posW, const float* __restrict__ posb,
                       char* __restrict__ ws) {
    const int t = threadIdx.x;            // one wave
    const int bs = blockIdx.x;
    const float* frow = (const float*)(ws + OFF_F0) + (size_t)bs * cD;
    float acc = posb[t];
    for (int k = 0; k < cD; k++) acc += frow[k] * posW[(size_t)k * cL + t];
    int idx = t;
    for (int off = 32; off; off >>= 1) {
        float ov = __shfl_down(acc, off, 64);
        int   oi = __shfl_down(idx, off, 64);
        if (ov > acc || (ov == acc && oi < idx)) { acc = ov; idx = oi; }
    }
    if (t == 0) ((int*)(ws + OFF_CLS))[bs] = idx;
}

// ---------------- K4: adjacency bitmask + initial per-row max ----------------
__global__ void k4_adj(char* __restrict__ ws) {
    __shared__ float rsv[256]; __shared__ int rsk[256];
    const int t = threadIdx.x;
    const int bs = blockIdx.x;
    const int b = bs >> 9, r = bs & 511;
    const int* cls = (const int*)(ws + OFF_CLS) + (size_t)b * cS;
    const float* SJ = (const float*)(ws + OFF_SJ) + (size_t)b * cS;
    const float sir = ((const float*)(ws + OFF_SI))[bs];
    const float c0 = ((const float*)(ws + OFF_SC))[0];
    unsigned long long* adjrow = (unsigned long long*)(ws + OFF_ADJ) + (size_t)bs * 8;
    const int cr = cls[r];
    float bv = -INFINITY; int bc = 0;
    for (int p = 0; p < 2; p++) {
        const int c = p * 256 + t;
        int dd = c - r; if (dd < 0) dd = -dd;
        const bool allowed = (c != r) && (dd == 1 || cls[c] == cr);
        unsigned long long m = __ballot(allowed);
        if ((t & 63) == 0) adjrow[p * 4 + (t >> 6)] = m;
        if (allowed) {
            float val = sir + SJ[c] + c0;
            if (val > bv || (val == bv && c < bc)) { bv = val; bc = c; }
        }
    }
    rsv[t] = bv; rsk[t] = bc; __syncthreads();
    for (int o = 128; o; o >>= 1) {
        if (t < o) {
            float s2 = rsv[t + o]; int k2 = rsk[t + o];
            if (s2 > rsv[t] || (s2 == rsv[t] && k2 < rsk[t])) { rsv[t] = s2; rsk[t] = k2; }
        }
        __syncthreads();
    }
    if (t == 0) { ((float*)(ws + OFF_RM))[bs] = rsv[0]; ((int*)(ws + OFF_RA))[bs] = rsk[0]; }
}

// ---------------- K5: parser ----------------------------------------------
// vs previous version:
//  * matvec broadcast moved from LDS (xls + 32x ds_read_b128/thread) to VALU
//    v_readlane (bit-exact same accumulation order) -> frees the LDS pipe
//  * all max/argmax reductions via DPP (order-independent -> bit-exact)
//  * barrier B4 removed: sin/sjn 8-value reduce replicated per-wave (same
//    tree -> bit-exact); SIl/SJl/par/tau updates done by thread t==bi in D;
//    nresc zeroed in the fold phase. 5 barriers/iter instead of 6.
__global__ void __launch_bounds__(cT, 2)
parse_main(const float* __restrict__ W1, const float* __restrict__ b1,
           char* __restrict__ ws, float* __restrict__ out) {
    const int t = threadIdx.x;
    const int b = blockIdx.x & 15;        // batch (8 blocks of a batch land on one XCD)
    const int g = blockIdx.x >> 4;        // 0..7
    const int d0 = g * 64;
    const int wv = t >> 6;                // wave id = ks group
    const int ln = t & 63;

    unsigned long long* F64[2] = {
        (unsigned long long*)(ws + OFF_F0) + (size_t)b * cS * cD / 2,
        (unsigned long long*)(ws + OFF_F1) + (size_t)b * cS * cD / 2 };
    unsigned* prog = (unsigned*)(ws + OFF_BAR) + (size_t)b * 256;   // counters at prog[g*32]
    const float* SCp = (const float*)(ws + OFF_SC);
    const float c0 = SCp[0], cu_c = SCp[1], cv_c = SCp[2];

    // replicated per-block state
    __shared__ unsigned long long AdjL[8 * 512];   // column-major: AdjL[w*512 + r]
    __shared__ float SIl[512], SJl[512], rmax[512];
    __shared__ int   rarg[512];
    __shared__ int   tau[512];                     // last merge step of row r (-1 = never)
    __shared__ unsigned char par[512];             // F-copy parity per row
    __shared__ float rsh[512];
    __shared__ float wsv[8];  __shared__ int wsk[8];
    __shared__ float ws_si[8], ws_sj[8];
    __shared__ int   s_bi, s_bj;
    __shared__ int   rescanList[516]; __shared__ int nresc;

    // W1 slice in registers: thread (wv, ln) holds W1[wv*128 .. +127][d0+ln]
    const int kbase = wv * 128;
    float w[128];
#pragma unroll
    for (int kk = 0; kk < 128; kk++) w[kk] = W1[(size_t)(kk + kbase) * cD + d0 + ln];

    // csi/csj constants matching this thread's 2 staged floats (x index xk, xk+1)
    const int xk = (wv & 3) * 128 + 2 * ln;
    const float* cu_base = (const float*)(ws + ((wv < 4) ? OFF_UA : OFF_UB));
    const float* cvb     = (const float*)(ws + ((wv < 4) ? OFF_VA : OFF_VB));
    const float cu0 = cu_base[xk], cu1 = cu_base[xk + 1];
    const float cv0 = cvb[xk],     cv1 = cvb[xk + 1];

    // replicated init
    SIl[t]  = ((const float*)(ws + OFF_SI))[b * cS + t];
    SJl[t]  = ((const float*)(ws + OFF_SJ))[b * cS + t];
    rmax[t] = ((const float*)(ws + OFF_RM))[b * cS + t];
    rarg[t] = ((const int*)(ws + OFF_RA))[b * cS + t];
    tau[t]  = -1;
    par[t]  = 0;
    float b1a = 0.f, b1b = 0.f;
    if (t < 32) { b1a = b1[d0 + 2 * t]; b1b = b1[d0 + 2 * t + 1]; }
    {
        const unsigned long long* AG =
            (const unsigned long long*)(ws + OFF_ADJ) + (size_t)b * cS * 8;
#pragma unroll
        for (int wq = 0; wq < 8; wq++) AdjL[wq * 512 + t] = AG[(size_t)t * 8 + wq];
    }
    bool myAlive = true;
    float tot = 0.f;
    if (t == 0) nresc = 0;

    // initial per-wave rowmax reduce -> wsv/wsk (DPP, result lane 63)
    {
        float av = rmax[t]; int ak = (t << 9) | (rarg[t] & 511);
        wave_max64(av, ak);
        if (ln == 63) { wsv[wv] = av; wsk[wv] = ak; }
    }
    __syncthreads();   // B1

    for (int it = 0; it < cS - 1; ++it) {
        // ---- A: wave0 final argmax + dependency poll ----
        if (wv == 0) {
            float fv = (ln < 8) ? wsv[ln] : -INFINITY;
            int   fk = (ln < 8) ? wsk[ln] : 0x7fffffff;
            dpp_max_step<0x111, 0xf>(fv, fk);
            dpp_max_step<0x112, 0xf>(fv, fk);
            dpp_max_step<0x114, 0xf>(fv, fk);          // lane 7 = reduce(l0..7)
            const int bk = __builtin_amdgcn_readlane(fk, 7);
            const int pbi = bk >> 9, pbj = bk & 511;
            const int ti = tau[pbi], tj = tau[pbj];
            const int need = (ti > tj ? ti : tj) + 1;
            if (need > 0) {
                const unsigned un = (unsigned)need;
                for (;;) {
                    unsigned v = 0xffffffffu;
                    if (ln < 8) v = __hip_atomic_load(prog + ln * 32, __ATOMIC_RELAXED,
                                                      __HIP_MEMORY_SCOPE_AGENT);
                    if (__ballot(v >= un) == ~0ull) break;
                    __builtin_amdgcn_s_sleep(1);
                }
            }
            if (ln == 0) {
                s_bi = pbi; s_bj = pbj;
                if (g == 0) {
                    const float bfv = __int_as_float(
                        __builtin_amdgcn_readlane(__float_as_int(fv), 7));
                    tot += bfv;
                    out[16 + b * 1022 + it * 2 + 0] = (float)pbi;
                    out[16 + b * 1022 + it * 2 + 1] = (float)pbj;
                }
            }
        }
        __syncthreads();   // B2
        const int bi = s_bi, bj = s_bj;

        // ---- C: wave-local load + csi/csj + readlane matvec ----
        const int myrow = (wv < 4) ? bi : bj;
        const int mypar = par[myrow];                  // wave-uniform LDS read
        unsigned long long xv = __hip_atomic_load(
            F64[mypar] + (size_t)myrow * 256 + (wv & 3) * 64 + ln,
            __ATOMIC_RELAXED, __HIP_MEMORY_SCOPE_AGENT);
        float2 f2; __builtin_memcpy(&f2, &xv, 8);
        // csi/csj partials (order-sensitive sum: keep exact shuffle tree)
        {
            float csi = f2.x * cu0 + f2.y * cu1;
            float csj = f2.x * cv0 + f2.y * cv1;
#pragma unroll
            for (int off = 32; off; off >>= 1) {
                csi += __shfl_down(csi, off, 64);
                csj += __shfl_down(csj, off, 64);
            }
            if (ln == 0) { ws_si[wv] = csi; ws_sj[wv] = csj; }
        }
        // matvec: broadcast staged x via v_readlane (VALU), bit-exact order:
        // x[4m]=lane(2m).x, x[4m+1]=lane(2m).y, x[4m+2]=lane(2m+1).x, x[4m+3]=lane(2m+1).y
        {
            const int ix = __float_as_int(f2.x), iy = __float_as_int(f2.y);
            float a0 = 0.f, a1 = 0.f, a2 = 0.f, a3 = 0.f;
#pragma unroll
            for (int m = 0; m < 32; m++) {
                const float q0 = __int_as_float(__builtin_amdgcn_readlane(ix, 2 * m));
                const float q1 = __int_as_float(__builtin_amdgcn_readlane(iy, 2 * m));
                const float q2 = __int_as_float(__builtin_amdgcn_readlane(ix, 2 * m + 1));
                const float q3 = __int_as_float(__builtin_amdgcn_readlane(iy, 2 * m + 1));
                a0 += w[4 * m + 0] * q0;
                a1 += w[4 * m + 1] * q1;
                a2 += w[4 * m + 2] * q2;
                a3 += w[4 * m + 3] * q3;
            }
            rsh[t] = (a0 + a1) + (a2 + a3);
        }
        __syncthreads();   // B3

        // ---- wave0: output gather + store (issue early, drain after D) ----
        if (wv == 0 && ln < 32) {
            float p0 = b1a, p1 = b1b;
#pragma unroll
            for (int q = 0; q < 8; q++) { p0 += rsh[q * 64 + 2 * ln]; p1 += rsh[q * 64 + 2 * ln + 1]; }
            float2 pp; pp.x = p0; pp.y = p1;
            unsigned long long pk; __builtin_memcpy(&pk, &pp, 8);
            __hip_atomic_store(F64[mypar ^ 1] + (size_t)bi * 256 + g * 32 + ln, pk,
                               __ATOMIC_RELAXED, __HIP_MEMORY_SCOPE_AGENT);
        }

        // ---- E: replicated sin/sjn (same tree as before -> bit-exact) ----
        float su = (ln < 8) ? ws_si[ln] : 0.f;
        float sv = (ln < 8) ? ws_sj[ln] : 0.f;
#pragma unroll
        for (int off = 4; off; off >>= 1) {
            su += __shfl_down(su, off, 64);
            sv += __shfl_down(sv, off, 64);
        }
        const float sn = __int_as_float(
            __builtin_amdgcn_readfirstlane(__float_as_int(su))) + cu_c;
        const float jn = __int_as_float(
            __builtin_amdgcn_readfirstlane(__float_as_int(sv))) + cv_c;

        // ---- D: replicated adjacency + incremental rowmax (LDS only) ----
        {
            const float sjn_ = jn;
            const int wbi = bi >> 6, wbj = bj >> 6;
            const unsigned long long mbi = 1ull << (bi & 63), mbj = 1ull << (bj & 63);
            const int r = t;
            if (r == bj) {
                if (myAlive) { myAlive = false; rmax[t] = -INFINITY; }
            } else if (r == bi) {
                // rebuild own row = (row_bi | row_bj) minus {bi,bj}
#pragma unroll
                for (int wq = 0; wq < 8; wq++) {
                    unsigned long long nw = AdjL[wq * 512 + bi] | AdjL[wq * 512 + bj];
                    if (wq == wbi) nw &= ~mbi;
                    if (wq == wbj) nw &= ~mbj;
                    AdjL[wq * 512 + bi] = nw;
                }
                int slot = atomicAdd(&nresc, 1); rescanList[slot] = bi;
                SIl[bi] = sn; SJl[bi] = jn; par[bi] ^= 1; tau[bi] = it;
            } else if (myAlive) {
                unsigned long long wi = AdjL[wbi * 512 + r];
                unsigned long long wj = (wbj == wbi) ? wi : AdjL[wbj * 512 + r];
                const bool nb = ((wi & mbi) | (wj & mbj)) != 0ull;
                if (wbi == wbj) {
                    AdjL[wbi * 512 + r] = (wi & ~(mbi | mbj)) | (nb ? mbi : 0ull);
                } else {
                    AdjL[wbi * 512 + r] = (wi & ~mbi) | (nb ? mbi : 0ull);
                    AdjL[wbj * 512 + r] = wj & ~mbj;
                }
                const int ra = rarg[t];
                if (ra == bi || ra == bj) {
                    int slot = atomicAdd(&nresc, 1); rescanList[slot] = r;
                } else if (nb) {
                    const float val = SIl[r] + sjn_ + c0;
                    if (val > rmax[t] || (val == rmax[t] && bi < ra)) { rmax[t] = val; rarg[t] = bi; }
                }
            }
        }
        // wave0: drain F store (ack absorbed by D work) + publish
        if (wv == 0) {
            asm volatile("s_waitcnt vmcnt(0)" ::: "memory");
            if (ln == 0)
                __hip_atomic_store(prog + g * 32, (unsigned)(it + 1), __ATOMIC_RELAXED,
                                   __HIP_MEMORY_SCOPE_AGENT);
        }
        __syncthreads();   // B5

        // ---- wave-parallel rescans (DPP reduce, result lane 63) ----
        const int nr = nresc;
        for (int q = wv; q < nr; q += 8) {
            const int r = rescanList[q];
            const float sir = SIl[r];
            float bv2 = -INFINITY; int bc2 = 0x7fffffff;
#pragma unroll
            for (int k = 0; k < 8; k++) {
                const unsigned long long word = AdjL[k * 512 + r];   // wave-uniform
                if ((word >> ln) & 1ull) {
                    const int c = k * 64 + ln;
                    const float val = sir + SJl[c] + c0;
                    if (val > bv2 || (val == bv2 && c < bc2)) { bv2 = val; bc2 = c; }
                }
            }
            wave_max64(bv2, bc2);
            if (ln == 63) { rmax[r] = bv2; rarg[r] = bc2; }
        }
        __syncthreads();   // B6

        // ---- fold next step's per-wave rowmax reduce (DPP) ----
        {
            float av = rmax[t]; int ak = (t << 9) | (rarg[t] & 511);
            wave_max64(av, ak);
            if (ln == 63) { wsv[wv] = av; wsk[wv] = ak; }
        }
        if (t == 0) nresc = 0;
        __syncthreads();   // B1
    }
    if (g == 0 && t == 0) out[b] = tot;
}

extern "C" void kernel_launch(void* const* d_in, const int* in_sizes, int n_in,
                              void* d_out, int out_size, void* d_ws, size_t ws_size,
                              hipStream_t stream) {
    const int*   token_ids = (const int*)d_in[0];
    const float* vocab_emb = (const float*)d_in[1];
    const float* pos_W     = (const float*)d_in[2];
    const float* pos_b     = (const float*)d_in[3];
    const float* W1        = (const float*)d_in[4];
    const float* b1        = (const float*)d_in[5];
    const float* w2        = (const float*)d_in[6];
    const float* b2        = (const float*)d_in[7];
    float* out = (float*)d_out;
    char*  ws  = (char*)d_ws;

    k1_uvc<<<1026, 256, 0, stream>>>(W1, b1, w2, b2, ws);
    k1b_proj<<<1025, 256, 0, stream>>>(W1, b1, ws);
    k2_feat<<<cB * cS, 256, 0, stream>>>(token_ids, vocab_emb, ws);
    k3_cls<<<cB * cS, 64, 0, stream>>>(pos_W, pos_b, ws);
    k4_adj<<<cB * cS, 256, 0, stream>>>(ws);

    // cooperative launch for the co-residency guarantee (custom waits inside)
    void* args[] = { (void*)&W1, (void*)&b1, (void*)&ws, (void*)&out };
    hipLaunchCooperativeKernel((void*)parse_main, dim3(cB * cG), dim3(cT),
                               args, 0, stream);
}

// Round 2
// 3035.446 us; speedup vs baseline: 1.4212x; 1.2559x over previous
//
#include <hip/hip_runtime.h>

#define cB 16
#define cS 512
#define cD 512
#define cL 64
#define cG 8      // blocks per batch
#define cT 1024   // threads per block (16 waves)

// ---------------- workspace layout (bytes) ----------------
constexpr size_t FCOPY   = (size_t)cB * cS * cD * 4;            // 16 MB per F copy
constexpr size_t OFF_F0  = 0;
constexpr size_t OFF_F1  = FCOPY;
constexpr size_t OFF_U   = 2 * FCOPY;                           // D f32
constexpr size_t OFF_V   = OFF_U  + 2048;
constexpr size_t OFF_UA  = OFF_V  + 2048;                       // W1a @ u
constexpr size_t OFF_UB  = OFF_UA + 2048;                       // W1b @ u
constexpr size_t OFF_VA  = OFF_UB + 2048;                       // W1a @ v
constexpr size_t OFF_VB  = OFF_VA + 2048;                       // W1b @ v
constexpr size_t OFF_SC  = OFF_VB + 2048;                       // [c0, cu, cv]
constexpr size_t OFF_SI  = OFF_SC + 64;                         // B*S f32
constexpr size_t OFF_SJ  = OFF_SI + (size_t)cB*cS*4;
constexpr size_t OFF_CLS = OFF_SJ + (size_t)cB*cS*4;
constexpr size_t OFF_ADJ = OFF_CLS+ (size_t)cB*cS*4;            // B*S*8 u64 (row-major)
constexpr size_t OFF_RM  = OFF_ADJ+ (size_t)cB*cS*64;
constexpr size_t OFF_RA  = OFF_RM + (size_t)cB*cS*4;
// prog: per batch 8 counters at 128B stride (no false sharing). 16 KB total.
constexpr size_t OFF_BAR = ((OFF_RA + (size_t)cB*cS*4 + 127) & ~(size_t)127);

// ---------------- DPP max+key reduction helpers (order-independent) ----------
template <int CTRL, int RMASK>
__device__ __forceinline__ void dpp_max_step(float& v, int& k) {
    const float ov = __int_as_float(__builtin_amdgcn_update_dpp(
        (int)0xff800000u, __float_as_int(v), CTRL, RMASK, 0xf, false));
    const int ok = __builtin_amdgcn_update_dpp(
        0x7fffffff, k, CTRL, RMASK, 0xf, false);
    if (ov > v || (ov == v && ok < k)) { v = ov; k = ok; }
}

// full 64-lane (value,key) max; result lands in lane 63
__device__ __forceinline__ void wave_max64(float& v, int& k) {
    dpp_max_step<0x111, 0xf>(v, k);   // row_shr:1
    dpp_max_step<0x112, 0xf>(v, k);   // row_shr:2
    dpp_max_step<0x114, 0xf>(v, k);   // row_shr:4
    dpp_max_step<0x118, 0xf>(v, k);   // row_shr:8
    dpp_max_step<0x142, 0xa>(v, k);   // row_bcast:15 rows 1,3
    dpp_max_step<0x143, 0xc>(v, k);   // row_bcast:31 rows 2,3
}

// x + (lane i+N value) for lanes where i+N stays in the 16-row; others add 0.
// Bit-exact replacement of __shfl_down(x, N) for N <= 8 in a down-sweep tree
// (only the prefix lanes feed later steps).
template <int N>
__device__ __forceinline__ float dpp_shl_add(float x) {
    const float o = __int_as_float(__builtin_amdgcn_update_dpp(
        0, __float_as_int(x), 0x100 + N /*row_shl:N*/, 0xf, 0xf, false));
    return x + o;
}

// ---------------- K1: u = W1a@w2, v = W1b@w2, c0 = b1@w2 + b2 ----------------
__global__ void k1_uvc(const float* __restrict__ W1, const float* __restrict__ b1,
                       const float* __restrict__ w2, const float* __restrict__ b2,
                       char* __restrict__ ws) {
    const int t = threadIdx.x;
    const int r = blockIdx.x;
    if (r == 1025) {   // zero progress counters (ws poisoned 0xAA pre-launch)
        unsigned* bar = (unsigned*)(ws + OFF_BAR);
        for (int i = t; i < 4096; i += 256) bar[i] = 0u;
        return;
    }
    __shared__ float rs[256];
    float acc;
    if (r < 1024) {
        const float* row = W1 + (size_t)r * cD;
        acc = row[t] * w2[t] + row[t + 256] * w2[t + 256];
    } else {
        acc = b1[t] * w2[t] + b1[t + 256] * w2[t + 256];
    }
    rs[t] = acc; __syncthreads();
    for (int o = 128; o; o >>= 1) { if (t < o) rs[t] += rs[t + o]; __syncthreads(); }
    if (t == 0) {
        if (r < 512)        ((float*)(ws + OFF_U))[r] = rs[0];
        else if (r < 1024)  ((float*)(ws + OFF_V))[r - 512] = rs[0];
        else                ((float*)(ws + OFF_SC))[0] = rs[0] + b2[0];   // c0
    }
}

// ---------------- K1b: ua/ub/va/vb = W1{a,b} @ {u,v};  cu = b1·u, cv = b1·v --------
__global__ void k1b_proj(const float* __restrict__ W1, const float* __restrict__ b1,
                         char* __restrict__ ws) {
    __shared__ float ru[256], rv[256];
    const int t = threadIdx.x;
    const int k = blockIdx.x;
    const float* U = (const float*)(ws + OFF_U);
    const float* V = (const float*)(ws + OFF_V);
    const float* row = (k < 1024) ? (W1 + (size_t)k * cD) : b1;
    ru[t] = row[t] * U[t] + row[t + 256] * U[t + 256];
    rv[t] = row[t] * V[t] + row[t + 256] * V[t + 256];
    __syncthreads();
    for (int o = 128; o; o >>= 1) {
        if (t < o) { ru[t] += ru[t + o]; rv[t] += rv[t + o]; }
        __syncthreads();
    }
    if (t == 0) {
        if (k < 512)       { ((float*)(ws + OFF_UA))[k] = ru[0]; ((float*)(ws + OFF_VA))[k] = rv[0]; }
        else if (k < 1024) { ((float*)(ws + OFF_UB))[k - 512] = ru[0]; ((float*)(ws + OFF_VB))[k - 512] = rv[0]; }
        else               { ((float*)(ws + OFF_SC))[1] = ru[0]; ((float*)(ws + OFF_SC))[2] = rv[0]; }
    }
}

// ---------------- K2: gather feats into F copy0, si = f@u, sj = f@v ----------------
__global__ void k2_feat(const int* __restrict__ tok, const float* __restrict__ emb,
                        char* __restrict__ ws) {
    __shared__ float ru[256], rv[256];
    const int t = threadIdx.x;
    const int bs = blockIdx.x;
    const float* U = (const float*)(ws + OFF_U);
    const float* V = (const float*)(ws + OFF_V);
    float* F = (float*)(ws + OFF_F0);
    const int tk = tok[bs];
    const float* src = emb + (size_t)tk * cD;
    float* dst = F + (size_t)bs * cD;
    const float e0 = src[t], e1 = src[t + 256];
    dst[t] = e0; dst[t + 256] = e1;
    ru[t] = e0 * U[t] + e1 * U[t + 256];
    rv[t] = e0 * V[t] + e1 * V[t + 256];
    __syncthreads();
    for (int o = 128; o; o >>= 1) {
        if (t < o) { ru[t] += ru[t + o]; rv[t] += rv[t + o]; }
        __syncthreads();
    }
    if (t == 0) {
        ((float*)(ws + OFF_SI))[bs] = ru[0];
        ((float*)(ws + OFF_SJ))[bs] = rv[0];
    }
}

// ---------------- K3: logits argmax -> cls ----------------
__global__ void k3_cls(const float* __restrict__ posW, const float* __restrict__ posb,
                       char* __restrict__ ws) {
    const int t = threadIdx.x;            // one wave
    const int bs = blockIdx.x;
    const float* frow = (const float*)(ws + OFF_F0) + (size_t)bs * cD;
    float acc = posb[t];
    for (int k = 0; k < cD; k++) acc += frow[k] * posW[(size_t)k * cL + t];
    int idx = t;
    for (int off = 32; off; off >>= 1) {
        float ov = __shfl_down(acc, off, 64);
        int   oi = __shfl_down(idx, off, 64);
        if (ov > acc || (ov == acc && oi < idx)) { acc = ov; idx = oi; }
    }
    if (t == 0) ((int*)(ws + OFF_CLS))[bs] = idx;
}

// ---------------- K4: adjacency bitmask + initial per-row max ----------------
__global__ void k4_adj(char* __restrict__ ws) {
    __shared__ float rsv[256]; __shared__ int rsk[256];
    const int t = threadIdx.x;
    const int bs = blockIdx.x;
    const int b = bs >> 9, r = bs & 511;
    const int* cls = (const int*)(ws + OFF_CLS) + (size_t)b * cS;
    const float* SJ = (const float*)(ws + OFF_SJ) + (size_t)b * cS;
    const float sir = ((const float*)(ws + OFF_SI))[bs];
    const float c0 = ((const float*)(ws + OFF_SC))[0];
    unsigned long long* adjrow = (unsigned long long*)(ws + OFF_ADJ) + (size_t)bs * 8;
    const int cr = cls[r];
    float bv = -INFINITY; int bc = 0;
    for (int p = 0; p < 2; p++) {
        const int c = p * 256 + t;
        int dd = c - r; if (dd < 0) dd = -dd;
        const bool allowed = (c != r) && (dd == 1 || cls[c] == cr);
        unsigned long long m = __ballot(allowed);
        if ((t & 63) == 0) adjrow[p * 4 + (t >> 6)] = m;
        if (allowed) {
            float val = sir + SJ[c] + c0;
            if (val > bv || (val == bv && c < bc)) { bv = val; bc = c; }
        }
    }
    rsv[t] = bv; rsk[t] = bc; __syncthreads();
    for (int o = 128; o; o >>= 1) {
        if (t < o) {
            float s2 = rsv[t + o]; int k2 = rsk[t + o];
            if (s2 > rsv[t] || (s2 == rsv[t] && k2 < rsk[t])) { rsv[t] = s2; rsk[t] = k2; }
        }
        __syncthreads();
    }
    if (t == 0) { ((float*)(ws + OFF_RM))[bs] = rsv[0]; ((int*)(ws + OFF_RA))[bs] = rsk[0]; }
}

// ---------------- K5: parser ----------------------------------------------
// vs previous version:
//  * 1024 threads / 16 waves: each old 128-k wave split into two 64-k half-
//    waves (h=0 computes a0,a1; h=1 computes a2,a3). wreg[64]/thread fits the
//    128-VGPR cap at 4 waves/SIMD -> no AGPR/scratch spill, 2x TLP.
//    FP tree is IDENTICAL: gather does p += (A+B), same association.
//  * csi/csj and E sums: off 8/4/2/1 via DPP row_shl (bit-exact), off 32/16
//    keep shfl -> 4 fewer ds_bpermute per chain.
//  * {bi,bj,par_i,par_j} packed into one LDS word by wave0 -> C phase loses
//    the dependent par[] lookup.
__global__ void __launch_bounds__(cT, 4)
parse_main(const float* __restrict__ W1, const float* __restrict__ b1,
           char* __restrict__ ws, float* __restrict__ out) {
    const int t  = threadIdx.x;           // 0..1023
    const int b  = blockIdx.x & 15;       // batch (blocks of a batch share an XCD)
    const int g  = blockIdx.x >> 4;       // 0..7
    const int d0 = g * 64;
    const int wf = t >> 6;                // wave id 0..15
    const int ln = t & 63;
    const int wv = wf >> 1;               // k-chunk 0..7 (old wave id)
    const int h  = wf & 1;                // half: 0 -> a0/a1, 1 -> a2/a3

    unsigned long long* F64[2] = {
        (unsigned long long*)(ws + OFF_F0) + (size_t)b * cS * cD / 2,
        (unsigned long long*)(ws + OFF_F1) + (size_t)b * cS * cD / 2 };
    unsigned* prog = (unsigned*)(ws + OFF_BAR) + (size_t)b * 256;   // counters at prog[g*32]
    const float* SCp = (const float*)(ws + OFF_SC);
    const float c0 = SCp[0], cu_c = SCp[1], cv_c = SCp[2];

    // replicated per-block state
    __shared__ unsigned long long AdjL[8 * 512];   // column-major: AdjL[w*512 + r]
    __shared__ float SIl[512], SJl[512], rmax[512];
    __shared__ int   rarg[512];
    __shared__ int   tau[512];                     // last merge step of row r (-1 = never)
    __shared__ unsigned char par[512];             // F-copy parity per row
    __shared__ float rsh[1024];
    __shared__ float wsv[8];  __shared__ int wsk[8];
    __shared__ float ws_si[8], ws_sj[8];
    __shared__ int   s_info;                       // bi | bj<<9 | par_i<<18 | par_j<<19
    __shared__ int   rescanList[516]; __shared__ int nresc;

    // W1 slice in registers: thread (wf,ln) holds 64 of the old wave's 128 k's
    // old wave wv covered k in [wv*128, wv*128+128); h=0 -> k%4 in {0,1},
    // h=1 -> k%4 in {2,3}.  wreg[2m+s] = W1[kbase + 4m + 2h + s][d0+ln]
    const int kbase = wv * 128;
    float wreg[64];
#pragma unroll
    for (int m = 0; m < 32; m++) {
        wreg[2 * m]     = W1[(size_t)(kbase + 4 * m + 2 * h)     * cD + d0 + ln];
        wreg[2 * m + 1] = W1[(size_t)(kbase + 4 * m + 2 * h + 1) * cD + d0 + ln];
    }

    // csi/csj constants (h==0 waves only; they see chunk dims (2ln, 2ln+1))
    const int xk = (wv & 3) * 128 + 2 * ln;
    float cu0 = 0.f, cu1 = 0.f, cv0 = 0.f, cv1 = 0.f;
    if (h == 0) {
        const float* cu_base = (const float*)(ws + ((wv < 4) ? OFF_UA : OFF_UB));
        const float* cvb     = (const float*)(ws + ((wv < 4) ? OFF_VA : OFF_VB));
        cu0 = cu_base[xk]; cu1 = cu_base[xk + 1];
        cv0 = cvb[xk];     cv1 = cvb[xk + 1];
    }

    // replicated init (rows live in t<512)
    if (t < cS) {
        SIl[t]  = ((const float*)(ws + OFF_SI))[b * cS + t];
        SJl[t]  = ((const float*)(ws + OFF_SJ))[b * cS + t];
        rmax[t] = ((const float*)(ws + OFF_RM))[b * cS + t];
        rarg[t] = ((const int*)(ws + OFF_RA))[b * cS + t];
        tau[t]  = -1;
        par[t]  = 0;
        const unsigned long long* AG =
            (const unsigned long long*)(ws + OFF_ADJ) + (size_t)b * cS * 8;
#pragma unroll
        for (int wq = 0; wq < 8; wq++) AdjL[wq * 512 + t] = AG[(size_t)t * 8 + wq];
    }
    float b1v = 0.f;
    if (t < 64) b1v = b1[d0 + t];          // wave0: one output dim per lane
    bool myAlive = true;
    float tot = 0.f;
    if (t == 0) nresc = 0;

    // initial per-row-group rowmax reduce -> wsv/wsk (DPP, result lane 63)
    if (t < cS) {
        float av = rmax[t]; int ak = (t << 9) | (rarg[t] & 511);
        wave_max64(av, ak);
        if (ln == 63) { wsv[wf] = av; wsk[wf] = ak; }
    }
    __syncthreads();   // B1

    for (int it = 0; it < cS - 1; ++it) {
        // ---- A: wave0 final argmax + dependency poll ----
        if (wf == 0) {
            float fv = (ln < 8) ? wsv[ln] : -INFINITY;
            int   fk = (ln < 8) ? wsk[ln] : 0x7fffffff;
            dpp_max_step<0x111, 0xf>(fv, fk);
            dpp_max_step<0x112, 0xf>(fv, fk);
            dpp_max_step<0x114, 0xf>(fv, fk);          // lane 7 = reduce(l0..7)
            const int bk = __builtin_amdgcn_readlane(fk, 7);
            const int pbi = bk >> 9, pbj = bk & 511;
            const int ti = tau[pbi], tj = tau[pbj];
            const int pi = (int)par[pbi], pj = (int)par[pbj];
            const int need = (ti > tj ? ti : tj) + 1;
            if (need > 0) {
                const unsigned un = (unsigned)need;
                for (;;) {
                    unsigned v = 0xffffffffu;
                    if (ln < 8) v = __hip_atomic_load(prog + ln * 32, __ATOMIC_RELAXED,
                                                      __HIP_MEMORY_SCOPE_AGENT);
                    if (__ballot(v >= un) == ~0ull) break;
                    __builtin_amdgcn_s_sleep(1);
                }
            }
            if (ln == 0) {
                s_info = pbi | (pbj << 9) | (pi << 18) | (pj << 19);
                if (g == 0) {
                    const float bfv = __int_as_float(
                        __builtin_amdgcn_readlane(__float_as_int(fv), 7));
                    tot += bfv;
                    out[16 + b * 1022 + it * 2 + 0] = (float)pbi;
                    out[16 + b * 1022 + it * 2 + 1] = (float)pbj;
                }
            }
        }
        __syncthreads();   // B2
        const int info = s_info;
        const int bi = info & 511, bj = (info >> 9) & 511;

        // ---- C: wave-local load + csi/csj + readlane matvec ----
        const int myrow  = (wv < 4) ? bi : bj;
        const int mypar  = (wv < 4) ? ((info >> 18) & 1) : ((info >> 19) & 1);
        unsigned long long xv = __hip_atomic_load(
            F64[mypar] + (size_t)myrow * 256 + (wv & 3) * 64 + ln,
            __ATOMIC_RELAXED, __HIP_MEMORY_SCOPE_AGENT);
        float2 f2; __builtin_memcpy(&f2, &xv, 8);
        // csi/csj partials (h==0 waves; same tree as before -> bit-exact)
        if (h == 0) {
            float csi = f2.x * cu0 + f2.y * cu1;
            float csj = f2.x * cv0 + f2.y * cv1;
            csi += __shfl_down(csi, 32, 64);  csj += __shfl_down(csj, 32, 64);
            csi += __shfl_down(csi, 16, 64);  csj += __shfl_down(csj, 16, 64);
            csi = dpp_shl_add<8>(csi);  csj = dpp_shl_add<8>(csj);
            csi = dpp_shl_add<4>(csi);  csj = dpp_shl_add<4>(csj);
            csi = dpp_shl_add<2>(csi);  csj = dpp_shl_add<2>(csj);
            csi = dpp_shl_add<1>(csi);  csj = dpp_shl_add<1>(csj);
            if (ln == 0) { ws_si[wv] = csi; ws_sj[wv] = csj; }
        }
        // matvec halves: h=0 -> a0,a1 (x[4m],x[4m+1] = lane 2m);
        //                h=1 -> a2,a3 (x[4m+2],x[4m+3] = lane 2m+1)
        {
            const int ix = __float_as_int(f2.x), iy = __float_as_int(f2.y);
            float aP = 0.f, aQ = 0.f;
            if (h == 0) {
#pragma unroll
                for (int m = 0; m < 32; m++) {
                    const float q0 = __int_as_float(__builtin_amdgcn_readlane(ix, 2 * m));
                    const float q1 = __int_as_float(__builtin_amdgcn_readlane(iy, 2 * m));
                    aP += wreg[2 * m] * q0;
                    aQ += wreg[2 * m + 1] * q1;
                }
            } else {
#pragma unroll
                for (int m = 0; m < 32; m++) {
                    const float q0 = __int_as_float(__builtin_amdgcn_readlane(ix, 2 * m + 1));
                    const float q1 = __int_as_float(__builtin_amdgcn_readlane(iy, 2 * m + 1));
                    aP += wreg[2 * m] * q0;
                    aQ += wreg[2 * m + 1] * q1;
                }
            }
            rsh[t] = aP + aQ;   // h=0: a0+a1, h=1: a2+a3
        }
        __syncthreads();   // B3

        // ---- wave0: output gather + store (issue early, drain after D) ----
        if (wf == 0) {
            float p = b1v;
#pragma unroll
            for (int q = 0; q < 8; q++)
                p += rsh[(2 * q) * 64 + ln] + rsh[(2 * q + 1) * 64 + ln];
            // ((b1+P0)+P1)... with P_q = (a0+a1)+(a2+a3): identical tree
            __hip_atomic_store((float*)F64[mypar ^ 1] + (size_t)bi * 512 + d0 + ln, p,
                               __ATOMIC_RELAXED, __HIP_MEMORY_SCOPE_AGENT);
        }

        // ---- E: replicated sin/sjn (same tree -> bit-exact) ----
        float su = (ln < 8) ? ws_si[ln] : 0.f;
        float sv = (ln < 8) ? ws_sj[ln] : 0.f;
        su = dpp_shl_add<4>(su);  sv = dpp_shl_add<4>(sv);
        su = dpp_shl_add<2>(su);  sv = dpp_shl_add<2>(sv);
        su = dpp_shl_add<1>(su);  sv = dpp_shl_add<1>(sv);
        const float sn = __int_as_float(
            __builtin_amdgcn_readfirstlane(__float_as_int(su))) + cu_c;
        const float jn = __int_as_float(
            __builtin_amdgcn_readfirstlane(__float_as_int(sv))) + cv_c;

        // ---- D: replicated adjacency + incremental rowmax (LDS only) ----
        if (t < cS) {
            const float sjn_ = jn;
            const int wbi = bi >> 6, wbj = bj >> 6;
            const unsigned long long mbi = 1ull << (bi & 63), mbj = 1ull << (bj & 63);
            const int r = t;
            if (r == bj) {
                if (myAlive) { myAlive = false; rmax[t] = -INFINITY; }
            } else if (r == bi) {
                // rebuild own row = (row_bi | row_bj) minus {bi,bj}
#pragma unroll
                for (int wq = 0; wq < 8; wq++) {
                    unsigned long long nw = AdjL[wq * 512 + bi] | AdjL[wq * 512 + bj];
                    if (wq == wbi) nw &= ~mbi;
                    if (wq == wbj) nw &= ~mbj;
                    AdjL[wq * 512 + bi] = nw;
                }
                int slot = atomicAdd(&nresc, 1); rescanList[slot] = bi;
                SIl[bi] = sn; SJl[bi] = jn; par[bi] ^= 1; tau[bi] = it;
            } else if (myAlive) {
                unsigned long long wi = AdjL[wbi * 512 + r];
                unsigned long long wj = (wbj == wbi) ? wi : AdjL[wbj * 512 + r];
                const bool nb = ((wi & mbi) | (wj & mbj)) != 0ull;
                if (wbi == wbj) {
                    AdjL[wbi * 512 + r] = (wi & ~(mbi | mbj)) | (nb ? mbi : 0ull);
                } else {
                    AdjL[wbi * 512 + r] = (wi & ~mbi) | (nb ? mbi : 0ull);
                    AdjL[wbj * 512 + r] = wj & ~mbj;
                }
                const int ra = rarg[t];
                if (ra == bi || ra == bj) {
                    int slot = atomicAdd(&nresc, 1); rescanList[slot] = r;
                } else if (nb) {
                    const float val = SIl[r] + sjn_ + c0;
                    if (val > rmax[t] || (val == rmax[t] && bi < ra)) { rmax[t] = val; rarg[t] = bi; }
                }
            }
        }
        // wave0: drain F store (ack absorbed by D work) + publish
        if (wf == 0) {
            asm volatile("s_waitcnt vmcnt(0)" ::: "memory");
            if (ln == 0)
                __hip_atomic_store(prog + g * 32, (unsigned)(it + 1), __ATOMIC_RELAXED,
                                   __HIP_MEMORY_SCOPE_AGENT);
        }
        __syncthreads();   // B5

        // ---- wave-parallel rescans (DPP reduce, result lane 63) ----
        const int nr = nresc;
        for (int q = wf; q < nr; q += 16) {
            const int r = rescanList[q];
            const float sir = SIl[r];
            float bv2 = -INFINITY; int bc2 = 0x7fffffff;
#pragma unroll
            for (int k = 0; k < 8; k++) {
                const unsigned long long word = AdjL[k * 512 + r];   // wave-uniform
                if ((word >> ln) & 1ull) {
                    const int c = k * 64 + ln;
                    const float val = sir + SJl[c] + c0;
                    if (val > bv2 || (val == bv2 && c < bc2)) { bv2 = val; bc2 = c; }
                }
            }
            wave_max64(bv2, bc2);
            if (ln == 63) { rmax[r] = bv2; rarg[r] = bc2; }
        }
        __syncthreads();   // B6

        // ---- fold next step's per-row-group rowmax reduce (DPP) ----
        if (t < cS) {
            float av = rmax[t]; int ak = (t << 9) | (rarg[t] & 511);
            wave_max64(av, ak);
            if (ln == 63) { wsv[wf] = av; wsk[wf] = ak; }
        }
        if (t == 0) nresc = 0;
        __syncthreads();   // B1
    }
    if (g == 0 && t == 0) out[b] = tot;
}

extern "C" void kernel_launch(void* const* d_in, const int* in_sizes, int n_in,
                              void* d_out, int out_size, void* d_ws, size_t ws_size,
                              hipStream_t stream) {
    const int*   token_ids = (const int*)d_in[0];
    const float* vocab_emb = (const float*)d_in[1];
    const float* pos_W     = (const float*)d_in[2];
    const float* pos_b     = (const float*)d_in[3];
    const float* W1        = (const float*)d_in[4];
    const float* b1        = (const float*)d_in[5];
    const float* w2        = (const float*)d_in[6];
    const float* b2        = (const float*)d_in[7];
    float* out = (float*)d_out;
    char*  ws  = (char*)d_ws;

    k1_uvc<<<1026, 256, 0, stream>>>(W1, b1, w2, b2, ws);
    k1b_proj<<<1025, 256, 0, stream>>>(W1, b1, ws);
    k2_feat<<<cB * cS, 256, 0, stream>>>(token_ids, vocab_emb, ws);
    k3_cls<<<cB * cS, 64, 0, stream>>>(pos_W, pos_b, ws);
    k4_adj<<<cB * cS, 256, 0, stream>>>(ws);

    // cooperative launch for the co-residency guarantee (custom waits inside)
    void* args[] = { (void*)&W1, (void*)&b1, (void*)&ws, (void*)&out };
    hipLaunchCooperativeKernel((void*)parse_main, dim3(cB * cG), dim3(cT),
                               args, 0, stream);
}